// Round 6
// baseline (344.510 us; speedup 1.0000x reference)
//
#include <hip/hip_runtime.h>
#include <stdint.h>
#include <limits.h>

// Flip to 0 if validation shows wrong RNG path (legacy non-partitionable threefry).
#define THREEFRY_PARTITIONABLE 1

#define NTK   1024           // threads per block: fused fallback
#define NWAVE (NTK/64)       // 16
#define NTK1  512            // threads per block: mega kernel (8 waves)
#define NW1   (NTK1/64)      // 8
#define NBUCK 4096           // histogram buckets (monotone float key >> 20)
#define CAP   2048           // fused fallback per-row candidate cap
#define CAPS  256            // per-split candidate cap (workspace)
#define CAPG  2048           // per-row gathered candidate cap (== SMAX*CAPS bound)
#define CAPF  512            // per-row filtered candidate cap
#define KMAX  512            // max supported top_k
#define SMAX  32
#define CHUNK_TARGET 16384   // ~elements per split block -> S=8 at V=128k

#if __has_builtin(__builtin_amdgcn_exp2f)
#define FAST_EXP2(x) __builtin_amdgcn_exp2f(x)
#else
#define FAST_EXP2(x) exp2f(x)
#endif

__device__ __forceinline__ uint32_t rotl32(uint32_t v, int r) {
  return (v << r) | (v >> (32 - r));
}
__device__ __forceinline__ void tfround(uint32_t& x0, uint32_t& x1, int r) {
  x0 += x1; x1 = rotl32(x1, r); x1 ^= x0;
}
// JAX threefry2x32: 20 rounds, rotations [13,15,26,6]/[17,29,16,24]
__device__ __forceinline__ void threefry2x32(uint32_t k0, uint32_t k1,
                                             uint32_t x0, uint32_t x1,
                                             uint32_t& o0, uint32_t& o1) {
  uint32_t k2 = k0 ^ k1 ^ 0x1BD11BDAu;
  x0 += k0; x1 += k1;
  tfround(x0,x1,13); tfround(x0,x1,15); tfround(x0,x1,26); tfround(x0,x1,6);
  x0 += k1; x1 += k2 + 1u;
  tfround(x0,x1,17); tfround(x0,x1,29); tfround(x0,x1,16); tfround(x0,x1,24);
  x0 += k2; x1 += k0 + 2u;
  tfround(x0,x1,13); tfround(x0,x1,15); tfround(x0,x1,26); tfround(x0,x1,6);
  x0 += k0; x1 += k1 + 3u;
  tfround(x0,x1,17); tfround(x0,x1,29); tfround(x0,x1,16); tfround(x0,x1,24);
  x0 += k1; x1 += k2 + 4u;
  tfround(x0,x1,13); tfround(x0,x1,15); tfround(x0,x1,26); tfround(x0,x1,6);
  x0 += k2; x1 += k0 + 5u;
  o0 = x0; o1 = x1;
}
// Exponential noise for flat element i: jax.random.exponential(fold_in(key(0),1))
__device__ __forceinline__ float jax_noise(uint32_t kn0, uint32_t kn1,
                                           unsigned long long i,
                                           unsigned long long total) {
  uint32_t o0, o1, bits;
#if THREEFRY_PARTITIONABLE
  threefry2x32(kn0, kn1, (uint32_t)(i >> 32), (uint32_t)(i & 0xFFFFFFFFull), o0, o1);
  bits = o0 ^ o1;
#else
  unsigned long long H = total >> 1;
  if (i < H) { threefry2x32(kn0, kn1, (uint32_t)i, (uint32_t)(i + H), o0, o1); bits = o0; }
  else       { threefry2x32(kn0, kn1, (uint32_t)(i - H), (uint32_t)i, o0, o1); bits = o1; }
#endif
  float u = __uint_as_float((bits >> 9) | 0x3f800000u) - 1.0f;  // [0,1)
  float e = -log1pf(-u);
  return fmaxf(e, 1e-10f);
}
// Monotone float -> uint32 key (total order preserving)
__device__ __forceinline__ uint32_t fkey(float f) {
  uint32_t u = __float_as_uint(f);
  return u ^ ((u >> 31) ? 0xFFFFFFFFu : 0x80000000u);
}
// Smallest float whose key >= keyT (bucket floor). keyT==0 -> -inf (emit all).
__device__ __forceinline__ float unfkey_floor(uint32_t keyT) {
  if (keyT == 0u) return -INFINITY;
  return __uint_as_float((keyT & 0x80000000u) ? (keyT ^ 0x80000000u) : ~keyT);
}
__device__ __forceinline__ int clamp_k(int k) {
  if (k < 1) k = 1;
  if (k > KMAX) k = KMAX;
  return k;
}

// Block-parallel suffix-scan of hist -> bucket of the rank-k largest entry.
// beta_sh must be pre-zeroed; hist filled and barrier'd before the call.
// Conservative when hist holds a subset (undercount -> lower bucket).
template<int NT, int NW>
__device__ __forceinline__ void block_kth_bucket(uint32_t* hist, uint32_t* wtot,
                                                 int* beta_sh, int k,
                                                 int tid, int lane, int wave) {
  constexpr int BPTc = NBUCK / NT;
  const int base = tid * BPTc;
  uint32_t tsum = 0;
#pragma unroll
  for (int j = 0; j < BPTc; j++) tsum += hist[base + j];
  uint32_t incl = tsum;                    // inclusive suffix over lanes >= lane
  for (int off = 1; off < 64; off <<= 1) {
    uint32_t v = __shfl_down(incl, off);
    if (lane + off < 64) incl += v;
  }
  if (lane == 0) wtot[wave] = incl;
  __syncthreads();
  uint32_t above = incl - tsum;            // threads strictly above (same wave)
  for (int w = wave + 1; w < NW; w++) above += wtot[w];
  if (above < (uint32_t)k && above + tsum >= (uint32_t)k) {
    uint32_t run = above;
    for (int j = BPTc - 1; j >= 0; j--) {
      run += hist[base + j];
      if (run >= (uint32_t)k) { *beta_sh = base + j; break; }
    }
  }
  __syncthreads();
}

// zero per-row arrival counters (ws is poisoned each iteration)
__global__ void sampler_init(int* __restrict__ rowCnt, int B) {
  int t = blockIdx.x * blockDim.x + threadIdx.x;
  if (t < B) rowCnt[t] = 0;
}

// ========= Mega kernel: split stream + last-block-per-row finalize =========
// Grid = B*S blocks of 512 threads; ~39KB LDS -> 4 blocks/CU -> whole grid
// co-resident (all 256 CUs stream). Phase 1 per block (round-0-proven core):
// 4-deep float4 stream, branchless top-2 on RAW logit bits (T>0, IEEE div
// monotone), f32 exp2 accs -> f64 wave fold; histogram of thread maxes ->
// conservative per-split kth bucket (subset undercount => floor <= true kth
// => emission superset); emit v0 from registers, rare rescan when v1 >= fT.
// Partials+candidates go to ws; release fence; atomicAdd(rowCnt[b]). The
// LAST-arriving block of each row runs Phase 2 in-place (acquire fence):
// gather + exact-count histogram -> filter to ~100 -> exact (p desc, idx asc)
// rank -> spec noise (parallel) + chunked serial cumsum -> wave argmax.
// Per-row finalize OVERLAPS other rows' streaming (no global barrier, no
// second full launch).
__global__ __launch_bounds__(NTK1)
void sampler_mega(const float* __restrict__ logits,
                  const float* __restrict__ temps,
                  const int* __restrict__ topk_ptr,
                  float* __restrict__ msArr,
                  double* __restrict__ dsumArr,
                  int* __restrict__ cntArr,
                  float2* __restrict__ pairs,
                  int* __restrict__ rowCnt,
                  int* __restrict__ out,
                  int B, int V, int S, int chunk) {
  const int blk = blockIdx.x;
  const int b = blk / S, sp = blk - b * S;
  const int tid = threadIdx.x, lane = tid & 63, wave = tid >> 6;

  __shared__ uint32_t hist[NBUCK];     // phase1 hist; phase2 exact hist; then sv/si/sc overlay
  __shared__ float cv[CAPG];
  __shared__ int   ci[CAPG];
  __shared__ float c2v[CAPF];
  __shared__ int   c2i[CAPF];
  __shared__ float c2p[CAPF];
  __shared__ float wm[NW1];
  __shared__ double wsum[NW1];
  __shared__ uint32_t wtot[NW1];
  __shared__ int   offL[SMAX + 1];
  __shared__ int   cnL[SMAX];
  __shared__ float msL[SMAX];
  __shared__ double dsL[SMAX];
  __shared__ int beta_sh, cnum_sh, L_sh, ticket_sh;
  __shared__ float m_sh, D_sh;

  if (tid == 0) { beta_sh = 0; cnum_sh = 0; }
  for (int i = tid; i < NBUCK; i += NTK1) hist[i] = 0;

  const float T = temps[b];
  const float cf = (float)(1.4426950408889634 / (double)T);  // log2e / T
  const int k = clamp_k(*topk_ptr);

  const int start = sp * chunk;
  const int end = min(start + chunk, V);
  const float* row = logits + (size_t)b * (size_t)V;
  const int n = (end > start) ? (end - start) : 0;
  const int n4 = n >> 2;                 // start is 4-aligned (chunk % 4 == 0)
  const float4* row4 = (const float4*)(row + start);

  // ---- Phase 1: stream (round-0 core: top-2 + 2 rotating f32 accs) ----
  float v0 = -INFINITY, v1 = -INFINITY;
  int   i0 = 0, i1 = 0;
  float acc0 = 0.f, acc1 = 0.f;

  auto proc = [&](float f, int idx) {
    bool gt0 = f > v0;
    bool gt1 = f > v1;
    float nv1 = gt0 ? v0 : (gt1 ? f : v1);
    int   ni1 = gt0 ? i0 : (gt1 ? idx : i1);
    v1 = nv1; i1 = ni1;
    v0 = gt0 ? f : v0;
    i0 = gt0 ? idx : i0;
  };
  auto proc4 = [&](float4 f, int vb) {
    proc(f.x, vb); proc(f.y, vb + 1); proc(f.z, vb + 2); proc(f.w, vb + 3);
    acc0 += FAST_EXP2(f.x * cf) + FAST_EXP2(f.z * cf);
    acc1 += FAST_EXP2(f.y * cf) + FAST_EXP2(f.w * cf);
  };

  int i = tid;
  for (; i + 3 * NTK1 < n4; i += 4 * NTK1) {
    float4 fa = row4[i];
    float4 fb = row4[i + NTK1];
    float4 fc = row4[i + 2 * NTK1];
    float4 fd = row4[i + 3 * NTK1];
    proc4(fa, start + i * 4);
    proc4(fb, start + (i + NTK1) * 4);
    proc4(fc, start + (i + 2 * NTK1) * 4);
    proc4(fd, start + (i + 3 * NTK1) * 4);
  }
  for (; i < n4; i += NTK1) {
    float4 fa = row4[i];
    proc4(fa, start + i * 4);
  }
  for (int v = start + n4 * 4 + tid; v < end; v += NTK1) {
    float f = row[v];
    proc(f, v);
    acc0 += FAST_EXP2(f * cf);
  }

  // wave reductions: split max + raw f64 exp2 sum
  float bm = v0;
  for (int off = 32; off; off >>= 1)
    bm = fmaxf(bm, __shfl_down(bm, off));
  if (lane == 0) wm[wave] = bm;

  double ds = (double)acc0 + (double)acc1;
  for (int off = 32; off; off >>= 1)
    ds += __shfl_down(ds, off);
  if (lane == 0) wsum[wave] = ds;

  if (v0 != -INFINITY) atomicAdd(&hist[fkey(v0) >> 20], 1u);
  __syncthreads();                        // hist zero + wm + wsum + hist atomics

  if (tid == 0) {
    float m_sp = wm[0];
#pragma unroll
    for (int w = 1; w < NW1; w++) m_sp = fmaxf(m_sp, wm[w]);
    msArr[blk] = m_sp;
    double t = 0.0;
    for (int w = 0; w < NW1; w++) t += wsum[w];
    dsumArr[blk] = t;                     // RAW (unscaled) exp2 sum
  }

  block_kth_bucket<NTK1, NW1>(hist, wtot, &beta_sh, k, tid, lane, wave);

  const float fT = unfkey_floor((uint32_t)beta_sh << 20);
  float2* myp = pairs + (size_t)blk * CAPS;

  // emit: registers for the common case, rescan only on >=2 hits (round-0)
  if (v0 >= fT) {
    if (v1 >= fT) {
      for (int i2 = tid; i2 < n4; i2 += NTK1) {   // L2-warm, few threads active
        float4 f = row4[i2];
        const int vb = start + i2 * 4;
        if (f.x >= fT) { int p = atomicAdd(&cnum_sh, 1); if (p < CAPS) myp[p] = make_float2(f.x, __int_as_float(vb)); }
        if (f.y >= fT) { int p = atomicAdd(&cnum_sh, 1); if (p < CAPS) myp[p] = make_float2(f.y, __int_as_float(vb + 1)); }
        if (f.z >= fT) { int p = atomicAdd(&cnum_sh, 1); if (p < CAPS) myp[p] = make_float2(f.z, __int_as_float(vb + 2)); }
        if (f.w >= fT) { int p = atomicAdd(&cnum_sh, 1); if (p < CAPS) myp[p] = make_float2(f.w, __int_as_float(vb + 3)); }
      }
      for (int v = start + n4 * 4 + tid; v < end; v += NTK1) {
        float f = row[v];
        if (f >= fT) { int p = atomicAdd(&cnum_sh, 1); if (p < CAPS) myp[p] = make_float2(f, __int_as_float(v)); }
      }
    } else {
      int p = atomicAdd(&cnum_sh, 1);
      if (p < CAPS) myp[p] = make_float2(v0, __int_as_float(i0));
    }
  }
  __syncthreads();
  if (tid == 0) cntArr[blk] = min(cnum_sh, CAPS);

  // ---- release: my stores -> visible; then signal arrival ----
  __threadfence();                        // each thread flushes its own stores
  __syncthreads();                        // all fences done (incl. tid0's cntArr)
  if (tid == 0) ticket_sh = atomicAdd(&rowCnt[b], 1);
  __syncthreads();
  if (ticket_sh != S - 1) return;         // not last: done
  __threadfence();                        // acquire: see all splits' stores

  // ================= Phase 2: finalize row b (last block) =================
  if (tid == 0) { beta_sh = 0; cnum_sh = 0; }
  if (tid < S) {
    msL[tid] = msArr[b * S + tid];
    dsL[tid] = dsumArr[b * S + tid];
    int c = cntArr[b * S + tid];
    cnL[tid] = (c < CAPS) ? c : CAPS;
  }
  for (int t = tid; t < NBUCK; t += NTK1) hist[t] = 0;
  __syncthreads();

  if (tid == 0) {
    int acc = 0;
    for (int j = 0; j < S; j++) { offL[j] = acc; acc += cnL[j]; }
    offL[S] = acc;
    float mg = msL[0];
    for (int j = 1; j < S; j++) mg = fmaxf(mg, msL[j]);
    double t = 0.0;
    for (int j = 0; j < S; j++) t += dsL[j];   // serial order: D bit-stable
    const double cd = 1.4426950408889634 / (double)T;
    D_sh = (float)(t * exp2(-(double)mg * cd));   // single f64 rescale per row
    m_sh = mg / T;     // == max over fl(l/T) (monotone IEEE division)
  }
  __syncthreads();

  const int TC = min(offL[S], CAPG);

  // gather all splits' candidates into LDS + exact-count histogram
  for (int t = tid; t < TC; t += NTK1) {
    int j = 0;
#pragma unroll
    for (int jj = 1; jj <= SMAX; jj++)
      if (jj <= S) j += (t >= offL[jj]);
    float2 pr = pairs[(size_t)(b * S + j) * CAPS + (t - offL[j])];
    cv[t] = pr.x;
    ci[t] = __float_as_int(pr.y);
    atomicAdd(&hist[fkey(pr.x) >> 20], 1u);
  }
  __syncthreads();

  block_kth_bucket<NTK1, NW1>(hist, wtot, &beta_sh, k, tid, lane, wave);
  // hist is DEAD from here; overlay sv/si/sc on it (3*KMAX <= NBUCK)
  float* sv = (float*)hist;
  int*   si = (int*)hist + KMAX;
  float* sc = (float*)hist + 2 * KMAX;

  // filter to >= global kth bucket floor (exact counts -> floor <= true kth
  // element's bucket -> keep set superset of row top-k)
  const float fT2 = unfkey_floor((uint32_t)beta_sh << 20);
  for (int t = tid; t < TC; t += NTK1) {
    float val = cv[t];
    if (val >= fT2) {
      int pos = atomicAdd(&cnum_sh, 1);
      if (pos < CAPF) { c2v[pos] = val; c2i[pos] = ci[t]; }
    }
  }
  __syncthreads();

  const int C = min(cnum_sh, CAPF);
  const float m = m_sh, D = D_sh;
  // exact-path p for the ~100 survivors: real IEEE div + libm expf
  for (int t = tid; t < C; t += NTK1)
    c2p[t] = expf(c2v[t] / T - m) / D;
  __syncthreads();

  // exact ranking: (p desc, idx asc) — JAX top_k / stable argsort tie rule
  for (int t = tid; t < C; t += NTK1) {
    float pi = c2p[t];
    int   ii = c2i[t];
    int r = 0;
    for (int j = 0; j < C; j++) {
      float pj = c2p[j];
      r += (pj > pi) || (pj == pi && c2i[j] < ii);
    }
    if (r < k) { sv[r] = pi; si[r] = ii; }
  }
  __syncthreads();

  const int kk = (k < C) ? k : C;

  // (a) speculative noise scores for ALL j < kk (parallel, overlaps cumsum)
  {
    uint32_t kn0, kn1;
    threefry2x32(0u, 0u, 0u, 1u, kn0, kn1);   // fold_in(key(0), 1)
    unsigned long long total = (unsigned long long)B * (unsigned long long)V;
    for (int j = tid; j < kk; j += NTK1) {
      unsigned long long flat = (unsigned long long)b * (unsigned long long)V
                              + (unsigned long long)si[j];
      sc[j] = sv[j] / jax_noise(kn0, kn1, flat, total);
    }
  }

  // (b) top-p: serial fp32 cumsum (EXACT left-to-right association),
  // LDS reads chunk-prefetched 8-at-a-time (over-read stays inside hist[]).
  if (tid == 0) {
    float cum = 0.f;
    int L = 1;
    bool stop = false;
    for (int j0 = 0; j0 < kk && !stop; j0 += 8) {
      float t0 = sv[j0],     t1 = sv[j0 + 1], t2 = sv[j0 + 2], t3 = sv[j0 + 3];
      float t4 = sv[j0 + 4], t5 = sv[j0 + 5], t6 = sv[j0 + 6], t7 = sv[j0 + 7];
      float tt[8] = {t0, t1, t2, t3, t4, t5, t6, t7};
#pragma unroll
      for (int q = 0; q < 8; q++) {
        int j = j0 + q;
        if (j >= kk) { stop = true; break; }
        cum += tt[q];
        if (j == 0) continue;
        if (cum <= 0.9f) L = j + 1;
        else { stop = true; break; }
      }
    }
    L_sh = L;
  }
  __syncthreads();

  // exact wave-parallel argmax over j < L: total order (score desc, idx asc)
  if (wave == 0) {
    const int L = L_sh;
    float bs = -1.0f;
    int   bi = INT_MAX;
    for (int j = lane; j < L; j += 64) {
      float s = sc[j];
      int   ix = si[j];
      if (s > bs || (s == bs && ix < bi)) { bs = s; bi = ix; }
    }
    for (int off = 32; off; off >>= 1) {
      float os = __shfl_down(bs, off);
      int   oi = __shfl_down(bi, off);
      if (os > bs || (os == bs && oi < bi)) { bs = os; bi = oi; }
    }
    if (lane == 0) out[b] = bi;
  }
}

// ========= Fallback: round-2 validated fused per-row kernel (ws too small) ===
__global__ __launch_bounds__(NTK, 1)
void sampler_fused(const float* __restrict__ logits,
                   const float* __restrict__ temps,
                   const int* __restrict__ topk_ptr,
                   int* __restrict__ out,
                   int B, int V) {
  const int b = blockIdx.x;
  const int tid = threadIdx.x, lane = tid & 63, wave = tid >> 6;

  __shared__ uint32_t hist[NBUCK];
  __shared__ float cv[CAP];
  __shared__ int   ci[CAP];
  __shared__ float cp[CAP];
  __shared__ float sv[KMAX];
  __shared__ int   si[KMAX];
  __shared__ float sc[KMAX];
  __shared__ float wm[NWAVE];
  __shared__ double wsum[NWAVE];
  __shared__ uint32_t wtot[NWAVE];
  __shared__ int beta_sh, cnum_sh, L_sh;
  __shared__ float m_sh, D_sh;

  if (tid == 0) { beta_sh = 0; cnum_sh = 0; }
  for (int i = tid; i < NBUCK; i += NTK) hist[i] = 0;
  __syncthreads();

  const float T = temps[b];
  const float cf = (float)(1.4426950408889634 / (double)T);
  const int k = clamp_k(*topk_ptr);
  const float* row = logits + (size_t)b * (size_t)V;
  const int n4 = ((V & 3) == 0) ? (V >> 2) : 0;
  const float4* row4 = (const float4*)row;

  float v0 = -INFINITY, v1 = -INFINITY, v2 = -INFINITY;
  int   i0 = 0, i1 = 0;
  float a0 = 0.f, a1 = 0.f, a2 = 0.f, a3 = 0.f;

  auto proc = [&](float f, int idx) {
    bool gt0 = f > v0;
    bool gt1 = f > v1;
    bool gt2 = f > v2;
    float nv2 = gt1 ? v1 : (gt2 ? f : v2);
    float nv1 = gt0 ? v0 : (gt1 ? f : v1);
    int   ni1 = gt0 ? i0 : (gt1 ? idx : i1);
    v2 = nv2;
    v1 = nv1; i1 = ni1;
    v0 = gt0 ? f : v0;
    i0 = gt0 ? idx : i0;
  };
  auto proc4 = [&](float4 f, int vb, float& a) {
    proc(f.x, vb); proc(f.y, vb + 1); proc(f.z, vb + 2); proc(f.w, vb + 3);
    a += (FAST_EXP2(f.x * cf) + FAST_EXP2(f.y * cf))
       + (FAST_EXP2(f.z * cf) + FAST_EXP2(f.w * cf));
  };

  int i = tid;
  for (; i + 7 * NTK < n4; i += 8 * NTK) {
    float4 f0 = row4[i];
    float4 f1 = row4[i + NTK];
    float4 f2 = row4[i + 2 * NTK];
    float4 f3 = row4[i + 3 * NTK];
    float4 f4 = row4[i + 4 * NTK];
    float4 f5 = row4[i + 5 * NTK];
    float4 f6 = row4[i + 6 * NTK];
    float4 f7 = row4[i + 7 * NTK];
    proc4(f0, i * 4, a0);
    proc4(f1, (i + NTK) * 4, a1);
    proc4(f2, (i + 2 * NTK) * 4, a2);
    proc4(f3, (i + 3 * NTK) * 4, a3);
    proc4(f4, (i + 4 * NTK) * 4, a0);
    proc4(f5, (i + 5 * NTK) * 4, a1);
    proc4(f6, (i + 6 * NTK) * 4, a2);
    proc4(f7, (i + 7 * NTK) * 4, a3);
  }
  for (; i + 3 * NTK < n4; i += 4 * NTK) {
    float4 fa = row4[i];
    float4 fb = row4[i + NTK];
    float4 fc = row4[i + 2 * NTK];
    float4 fd = row4[i + 3 * NTK];
    proc4(fa, i * 4, a0);
    proc4(fb, (i + NTK) * 4, a1);
    proc4(fc, (i + 2 * NTK) * 4, a2);
    proc4(fd, (i + 3 * NTK) * 4, a3);
  }
  for (; i < n4; i += NTK) {
    float4 fa = row4[i];
    proc4(fa, i * 4, a0);
  }
  for (int v = n4 * 4 + tid; v < V; v += NTK) {
    float f = row[v];
    proc(f, v);
    a0 += FAST_EXP2(f * cf);
  }

  float bm = v0;
  for (int off = 32; off; off >>= 1)
    bm = fmaxf(bm, __shfl_down(bm, off));
  if (lane == 0) wm[wave] = bm;

  double ds = ((double)a0 + (double)a1) + ((double)a2 + (double)a3);
  for (int off = 32; off; off >>= 1)
    ds += __shfl_down(ds, off);
  if (lane == 0) wsum[wave] = ds;

  if (v0 != -INFINITY) atomicAdd(&hist[fkey(v0) >> 20], 1u);
  if (v1 != -INFINITY) atomicAdd(&hist[fkey(v1) >> 20], 1u);
  __syncthreads();

  if (tid == 0) {
    float mg = wm[0];
#pragma unroll
    for (int w = 1; w < NWAVE; w++) mg = fmaxf(mg, wm[w]);
    double t = 0.0;
    for (int w = 0; w < NWAVE; w++) t += wsum[w];
    const double cd = 1.4426950408889634 / (double)T;
    D_sh = (float)(t * exp2(-(double)mg * cd));
    m_sh = mg / T;
  }

  block_kth_bucket<NTK, NWAVE>(hist, wtot, &beta_sh, k, tid, lane, wave);

  const float fT = unfkey_floor((uint32_t)beta_sh << 20);
  auto emit1 = [&](float f, int idx) {
    if (f >= fT) {
      int p = atomicAdd(&cnum_sh, 1);
      if (p < CAP) { cv[p] = f; ci[p] = idx; }
    }
  };
  if (v2 >= fT) {
    for (int i2 = tid; i2 < n4; i2 += NTK) {
      float4 f = row4[i2];
      const int vb = i2 * 4;
      emit1(f.x, vb); emit1(f.y, vb + 1); emit1(f.z, vb + 2); emit1(f.w, vb + 3);
    }
    for (int v = n4 * 4 + tid; v < V; v += NTK) emit1(row[v], v);
  } else {
    if (v0 >= fT) { int p = atomicAdd(&cnum_sh, 1); if (p < CAP) { cv[p] = v0; ci[p] = i0; } }
    if (v1 >= fT) { int p = atomicAdd(&cnum_sh, 1); if (p < CAP) { cv[p] = v1; ci[p] = i1; } }
  }
  __syncthreads();

  const int C = min(cnum_sh, CAP);
  const float m = m_sh, D = D_sh;
  for (int t = tid; t < C; t += NTK)
    cp[t] = expf(cv[t] / T - m) / D;
  __syncthreads();

  for (int t = tid; t < C; t += NTK) {
    float pi = cp[t];
    int   ii = ci[t];
    int r = 0;
    for (int j = 0; j < C; j++) {
      float pj = cp[j];
      r += (pj > pi) || (pj == pi && ci[j] < ii);
    }
    if (r < k) { sv[r] = pi; si[r] = ii; }
  }
  __syncthreads();

  const int kk = (k < C) ? k : C;
  {
    uint32_t kn0, kn1;
    threefry2x32(0u, 0u, 0u, 1u, kn0, kn1);
    unsigned long long total = (unsigned long long)B * (unsigned long long)V;
    for (int j = tid; j < kk; j += NTK) {
      unsigned long long flat = (unsigned long long)b * (unsigned long long)V
                              + (unsigned long long)si[j];
      sc[j] = sv[j] / jax_noise(kn0, kn1, flat, total);
    }
  }
  if (tid == 0) {
    float cum = 0.f;
    int L = 1;
    bool stop = false;
    for (int j0 = 0; j0 < kk && !stop; j0 += 8) {
      float t0 = sv[j0],     t1 = sv[j0 + 1], t2 = sv[j0 + 2], t3 = sv[j0 + 3];
      float t4 = sv[j0 + 4], t5 = sv[j0 + 5], t6 = sv[j0 + 6], t7 = sv[j0 + 7];
      float tt[8] = {t0, t1, t2, t3, t4, t5, t6, t7};
#pragma unroll
      for (int q = 0; q < 8; q++) {
        int j = j0 + q;
        if (j >= kk) { stop = true; break; }
        cum += tt[q];
        if (j == 0) continue;
        if (cum <= 0.9f) L = j + 1;
        else { stop = true; break; }
      }
    }
    L_sh = L;
  }
  __syncthreads();

  if (wave == 0) {
    const int L = L_sh;
    float bs = -1.0f;
    int   bi = INT_MAX;
    for (int j = lane; j < L; j += 64) {
      float s = sc[j];
      int   ix = si[j];
      if (s > bs || (s == bs && ix < bi)) { bs = s; bi = ix; }
    }
    for (int off = 32; off; off >>= 1) {
      float os = __shfl_down(bs, off);
      int   oi = __shfl_down(bi, off);
      if (os > bs || (os == bs && oi < bi)) { bs = os; bi = oi; }
    }
    if (lane == 0) out[b] = bi;
  }
}

extern "C" void kernel_launch(void* const* d_in, const int* in_sizes, int n_in,
                              void* d_out, int out_size, void* d_ws, size_t ws_size,
                              hipStream_t stream) {
  const float* logits = (const float*)d_in[0];
  const float* temps  = (const float*)d_in[1];
  const int*   topk   = (const int*)d_in[2];
  int* out = (int*)d_out;

  int B = in_sizes[1];
  int V = in_sizes[0] / B;

  // ~16k elements per split block: B*S = 1024 blocks of 512 across 256 CUs.
  int S = (V + CHUNK_TARGET - 1) / CHUNK_TARGET;
  if (S > SMAX) S = SMAX;
  if (S < 1) S = 1;
  size_t need;
  for (;;) {
    need = (size_t)B * S * (sizeof(double) + sizeof(float) + sizeof(int))
         + (size_t)B * S * CAPS * sizeof(float2)
         + (size_t)B * sizeof(int);
    if (need <= ws_size || S <= 2) break;
    S >>= 1;
  }

  if (ws_size < need || S < 2) {
    sampler_fused<<<dim3(B), dim3(NTK), 0, stream>>>(logits, temps, topk, out, B, V);
    return;
  }

  int chunk = (((V + S - 1) / S) + 3) & ~3;   // multiple of 4 for float4 paths

  double* dsumArr = (double*)d_ws;
  float*  msArr   = (float*)(dsumArr + (size_t)B * S);
  int*    cntArr  = (int*)(msArr + (size_t)B * S);
  float2* pairs   = (float2*)(cntArr + (size_t)B * S);
  int*    rowCnt  = (int*)(pairs + (size_t)B * S * CAPS);

  sampler_init<<<dim3((B + 255) / 256), dim3(256), 0, stream>>>(rowCnt, B);
  sampler_mega<<<dim3(B * S), dim3(NTK1), 0, stream>>>(
      logits, temps, topk, msArr, dsumArr, cntArr, pairs, rowCnt, out, B, V, S, chunk);
}

// Round 7
// 109.267 us; speedup vs baseline: 3.1529x; 3.1529x over previous
//
#include <hip/hip_runtime.h>
#include <stdint.h>
#include <limits.h>

// Flip to 0 if validation shows wrong RNG path (legacy non-partitionable threefry).
#define THREEFRY_PARTITIONABLE 1

#define NTK   1024           // threads per block: 16 waves, one block per row
#define NWAVE (NTK/64)       // 16
#define NBUCK 4096           // histogram buckets (monotone float key >> 20)
#define BPT   (NBUCK/NTK)    // buckets per thread in the block scan (4)
#define CAP   2048           // per-row candidate cap (LDS); expected C ~150-400
#define KMAX  512            // max supported top_k

#if __has_builtin(__builtin_amdgcn_exp2f)
#define FAST_EXP2(x) __builtin_amdgcn_exp2f(x)
#else
#define FAST_EXP2(x) exp2f(x)
#endif

__device__ __forceinline__ uint32_t rotl32(uint32_t v, int r) {
  return (v << r) | (v >> (32 - r));
}
__device__ __forceinline__ void tfround(uint32_t& x0, uint32_t& x1, int r) {
  x0 += x1; x1 = rotl32(x1, r); x1 ^= x0;
}
// JAX threefry2x32: 20 rounds, rotations [13,15,26,6]/[17,29,16,24]
__device__ __forceinline__ void threefry2x32(uint32_t k0, uint32_t k1,
                                             uint32_t x0, uint32_t x1,
                                             uint32_t& o0, uint32_t& o1) {
  uint32_t k2 = k0 ^ k1 ^ 0x1BD11BDAu;
  x0 += k0; x1 += k1;
  tfround(x0,x1,13); tfround(x0,x1,15); tfround(x0,x1,26); tfround(x0,x1,6);
  x0 += k1; x1 += k2 + 1u;
  tfround(x0,x1,17); tfround(x0,x1,29); tfround(x0,x1,16); tfround(x0,x1,24);
  x0 += k2; x1 += k0 + 2u;
  tfround(x0,x1,13); tfround(x0,x1,15); tfround(x0,x1,26); tfround(x0,x1,6);
  x0 += k0; x1 += k1 + 3u;
  tfround(x0,x1,17); tfround(x0,x1,29); tfround(x0,x1,16); tfround(x0,x1,24);
  x0 += k1; x1 += k2 + 4u;
  tfround(x0,x1,13); tfround(x0,x1,15); tfround(x0,x1,26); tfround(x0,x1,6);
  x0 += k2; x1 += k0 + 5u;
  o0 = x0; o1 = x1;
}
// Exponential noise for flat element i: jax.random.exponential(fold_in(key(0),1))
__device__ __forceinline__ float jax_noise(uint32_t kn0, uint32_t kn1,
                                           unsigned long long i,
                                           unsigned long long total) {
  uint32_t o0, o1, bits;
#if THREEFRY_PARTITIONABLE
  threefry2x32(kn0, kn1, (uint32_t)(i >> 32), (uint32_t)(i & 0xFFFFFFFFull), o0, o1);
  bits = o0 ^ o1;
#else
  unsigned long long H = total >> 1;
  if (i < H) { threefry2x32(kn0, kn1, (uint32_t)i, (uint32_t)(i + H), o0, o1); bits = o0; }
  else       { threefry2x32(kn0, kn1, (uint32_t)(i - H), (uint32_t)i, o0, o1); bits = o1; }
#endif
  float u = __uint_as_float((bits >> 9) | 0x3f800000u) - 1.0f;  // [0,1)
  float e = -log1pf(-u);
  return fmaxf(e, 1e-10f);
}
// Monotone float -> uint32 key (total order preserving)
__device__ __forceinline__ uint32_t fkey(float f) {
  uint32_t u = __float_as_uint(f);
  return u ^ ((u >> 31) ? 0xFFFFFFFFu : 0x80000000u);
}
// Smallest float whose key >= keyT (bucket floor). keyT==0 -> -inf (emit all).
__device__ __forceinline__ float unfkey_floor(uint32_t keyT) {
  if (keyT == 0u) return -INFINITY;
  return __uint_as_float((keyT & 0x80000000u) ? (keyT ^ 0x80000000u) : ~keyT);
}
__device__ __forceinline__ int clamp_k(int k) {
  if (k < 1) k = 1;
  if (k > KMAX) k = KMAX;
  return k;
}

// Block-parallel suffix-scan of hist -> bucket of the rank-k largest entry.
// beta_sh must be pre-zeroed; hist filled and barrier'd before the call.
// Conservative when hist holds a subset (undercount -> lower bucket).
__device__ __forceinline__ void block_kth_bucket(uint32_t* hist, uint32_t* wtot,
                                                 int* beta_sh, int k,
                                                 int tid, int lane, int wave) {
  const int base = tid * BPT;
  uint32_t tsum = 0;
#pragma unroll
  for (int j = 0; j < BPT; j++) tsum += hist[base + j];
  uint32_t incl = tsum;                    // inclusive suffix over lanes >= lane
  for (int off = 1; off < 64; off <<= 1) {
    uint32_t v = __shfl_down(incl, off);
    if (lane + off < 64) incl += v;
  }
  if (lane == 0) wtot[wave] = incl;
  __syncthreads();
  uint32_t above = incl - tsum;            // threads strictly above (same wave)
  for (int w = wave + 1; w < NWAVE; w++) above += wtot[w];
  if (above < (uint32_t)k && above + tsum >= (uint32_t)k) {
    uint32_t run = above;
    for (int j = BPT - 1; j >= 0; j--) {
      run += hist[base + j];
      if (run >= (uint32_t)k) { *beta_sh = base + j; break; }
    }
  }
  __syncthreads();
}

// ========= Fused per-row sampler: one block per row, no workspace =========
// Round-2-validated kernel (109.9us total) with ONE change: the stream loop
// is software-pipelined — the next 8-float4 chunk's loads are issued BEFORE
// processing the current chunk, so each wave keeps 8-16 loads in flight in
// steady state instead of burst-then-drain (round-1 counters: VALUBusy 11%,
// latency-bound). Processing order, acc mapping (group j -> acc j&3), top-3
// chain and all tails are unchanged -> bit-identical results.
__global__ __launch_bounds__(NTK, 1)
void sampler_fused(const float* __restrict__ logits,
                   const float* __restrict__ temps,
                   const int* __restrict__ topk_ptr,
                   int* __restrict__ out,
                   int B, int V) {
  const int b = blockIdx.x;
  const int tid = threadIdx.x, lane = tid & 63, wave = tid >> 6;

  __shared__ uint32_t hist[NBUCK];
  __shared__ float cv[CAP];
  __shared__ int   ci[CAP];
  __shared__ float cp[CAP];
  __shared__ float sv[KMAX];
  __shared__ int   si[KMAX];   // directly after sv: cumsum chunk over-read lands here (benign)
  __shared__ float sc[KMAX];
  __shared__ float wm[NWAVE];
  __shared__ double wsum[NWAVE];
  __shared__ uint32_t wtot[NWAVE];
  __shared__ int beta_sh, cnum_sh, L_sh;
  __shared__ float m_sh, D_sh;

  if (tid == 0) { beta_sh = 0; cnum_sh = 0; }
  for (int i = tid; i < NBUCK; i += NTK) hist[i] = 0;
  __syncthreads();                         // hist zeroed before any atomics

  const float T = temps[b];
  const float cf = (float)(1.4426950408889634 / (double)T);  // log2e / T
  const int k = clamp_k(*topk_ptr);
  const float* row = logits + (size_t)b * (size_t)V;
  const int n4 = ((V & 3) == 0) ? (V >> 2) : 0;   // float4 path only if aligned
  const float4* row4 = (const float4*)row;

  // per-thread state: branchless top-3 (3rd is value-only) + exp2 accumulators
  float v0 = -INFINITY, v1 = -INFINITY, v2 = -INFINITY;
  int   i0 = 0, i1 = 0;
  float a0 = 0.f, a1 = 0.f, a2 = 0.f, a3 = 0.f;

  auto proc = [&](float f, int idx) {
    bool gt0 = f > v0;
    bool gt1 = f > v1;
    bool gt2 = f > v2;
    float nv2 = gt1 ? v1 : (gt2 ? f : v2);
    float nv1 = gt0 ? v0 : (gt1 ? f : v1);
    int   ni1 = gt0 ? i0 : (gt1 ? idx : i1);
    v2 = nv2;
    v1 = nv1; i1 = ni1;
    v0 = gt0 ? f : v0;
    i0 = gt0 ? idx : i0;
  };
  auto proc4 = [&](float4 f, int vb, float& a) {
    proc(f.x, vb); proc(f.y, vb + 1); proc(f.z, vb + 2); proc(f.w, vb + 3);
    a += (FAST_EXP2(f.x * cf) + FAST_EXP2(f.y * cf))
       + (FAST_EXP2(f.z * cf) + FAST_EXP2(f.w * cf));
  };

  // ---- streaming pass: software-pipelined 8-chunk (next chunk's 8 loads
  // issued before processing current chunk -> 8-16 loads in flight) ----
  int i = tid;
  if (i + 7 * NTK < n4) {
    // prologue: load chunk A
    float4 A0 = row4[i];
    float4 A1 = row4[i + NTK];
    float4 A2 = row4[i + 2 * NTK];
    float4 A3 = row4[i + 3 * NTK];
    float4 A4 = row4[i + 4 * NTK];
    float4 A5 = row4[i + 5 * NTK];
    float4 A6 = row4[i + 6 * NTK];
    float4 A7 = row4[i + 7 * NTK];
    int ia = i;
    i += 8 * NTK;
    while (i + 7 * NTK < n4) {
      // issue next chunk's loads FIRST (stay in flight across processing)
      float4 B0 = row4[i];
      float4 B1 = row4[i + NTK];
      float4 B2 = row4[i + 2 * NTK];
      float4 B3 = row4[i + 3 * NTK];
      float4 B4 = row4[i + 4 * NTK];
      float4 B5 = row4[i + 5 * NTK];
      float4 B6 = row4[i + 6 * NTK];
      float4 B7 = row4[i + 7 * NTK];
      // process current chunk (same order + acc mapping as round 2)
      proc4(A0, ia * 4, a0);
      proc4(A1, (ia + NTK) * 4, a1);
      proc4(A2, (ia + 2 * NTK) * 4, a2);
      proc4(A3, (ia + 3 * NTK) * 4, a3);
      proc4(A4, (ia + 4 * NTK) * 4, a0);
      proc4(A5, (ia + 5 * NTK) * 4, a1);
      proc4(A6, (ia + 6 * NTK) * 4, a2);
      proc4(A7, (ia + 7 * NTK) * 4, a3);
      A0 = B0; A1 = B1; A2 = B2; A3 = B3;
      A4 = B4; A5 = B5; A6 = B6; A7 = B7;
      ia = i;
      i += 8 * NTK;
    }
    // epilogue: process last full chunk
    proc4(A0, ia * 4, a0);
    proc4(A1, (ia + NTK) * 4, a1);
    proc4(A2, (ia + 2 * NTK) * 4, a2);
    proc4(A3, (ia + 3 * NTK) * 4, a3);
    proc4(A4, (ia + 4 * NTK) * 4, a0);
    proc4(A5, (ia + 5 * NTK) * 4, a1);
    proc4(A6, (ia + 6 * NTK) * 4, a2);
    proc4(A7, (ia + 7 * NTK) * 4, a3);
  }
  for (; i + 3 * NTK < n4; i += 4 * NTK) {
    float4 fa = row4[i];
    float4 fb = row4[i + NTK];
    float4 fc = row4[i + 2 * NTK];
    float4 fd = row4[i + 3 * NTK];
    proc4(fa, i * 4, a0);
    proc4(fb, (i + NTK) * 4, a1);
    proc4(fc, (i + 2 * NTK) * 4, a2);
    proc4(fd, (i + 3 * NTK) * 4, a3);
  }
  for (; i < n4; i += NTK) {
    float4 fa = row4[i];
    proc4(fa, i * 4, a0);
  }
  for (int v = n4 * 4 + tid; v < V; v += NTK) {
    float f = row[v];
    proc(f, v);
    a0 += FAST_EXP2(f * cf);
  }

  // wave reductions: block max + raw f64 exp2 sum
  float bm = v0;
  for (int off = 32; off; off >>= 1)
    bm = fmaxf(bm, __shfl_down(bm, off));
  if (lane == 0) wm[wave] = bm;

  double ds = ((double)a0 + (double)a1) + ((double)a2 + (double)a3);
  for (int off = 32; off; off >>= 1)
    ds += __shfl_down(ds, off);
  if (lane == 0) wsum[wave] = ds;

  // histogram thread top-2 (subset of row -> conservative threshold)
  if (v0 != -INFINITY) atomicAdd(&hist[fkey(v0) >> 20], 1u);
  if (v1 != -INFINITY) atomicAdd(&hist[fkey(v1) >> 20], 1u);
  __syncthreads();                         // wm + wsum + hist atomics

  if (tid == 0) {
    float mg = wm[0];
#pragma unroll
    for (int w = 1; w < NWAVE; w++) mg = fmaxf(mg, wm[w]);
    double t = 0.0;
    for (int w = 0; w < NWAVE; w++) t += wsum[w];   // serial order: D bit-stable
    const double cd = 1.4426950408889634 / (double)T;
    D_sh = (float)(t * exp2(-(double)mg * cd));   // single f64 rescale per row
    m_sh = mg / T;     // == max over fl(l/T) (monotone IEEE division)
  }

  block_kth_bucket(hist, wtot, &beta_sh, k, tid, lane, wave);

  // ---- emit: registers for <=2 hits; rare 4-deep-pipelined rescan for >=3 ----
  // Emission set = ALL elements >= fT (exact), a superset of the row top-k.
  const float fT = unfkey_floor((uint32_t)beta_sh << 20);
  auto emit1 = [&](float f, int idx) {
    if (f >= fT) {
      int p = atomicAdd(&cnum_sh, 1);
      if (p < CAP) { cv[p] = f; ci[p] = idx; }
    }
  };
  auto emit4 = [&](float4 f, int vb) {
    emit1(f.x, vb); emit1(f.y, vb + 1); emit1(f.z, vb + 2); emit1(f.w, vb + 3);
  };
  if (v2 >= fT) {
    // rare (~few threads/block): >=3 elements above threshold -> exact rescan
    // of this thread's strided slice (pipelined 4-deep; L2/L3-warm)
    int i2 = tid;
    for (; i2 + 3 * NTK < n4; i2 += 4 * NTK) {
      float4 fa = row4[i2];
      float4 fb = row4[i2 + NTK];
      float4 fc = row4[i2 + 2 * NTK];
      float4 fd = row4[i2 + 3 * NTK];
      emit4(fa, i2 * 4);
      emit4(fb, (i2 + NTK) * 4);
      emit4(fc, (i2 + 2 * NTK) * 4);
      emit4(fd, (i2 + 3 * NTK) * 4);
    }
    for (; i2 < n4; i2 += NTK) {
      float4 fa = row4[i2];
      emit4(fa, i2 * 4);
    }
    for (int v = n4 * 4 + tid; v < V; v += NTK) {
      float f = row[v];
      emit1(f, v);
    }
  } else {
    // common case: top-2 registers carry every element of this thread >= fT
    if (v0 >= fT) { int p = atomicAdd(&cnum_sh, 1); if (p < CAP) { cv[p] = v0; ci[p] = i0; } }
    if (v1 >= fT) { int p = atomicAdd(&cnum_sh, 1); if (p < CAP) { cv[p] = v1; ci[p] = i1; } }
  }
  __syncthreads();

  const int C = min(cnum_sh, CAP);
  const float m = m_sh, D = D_sh;
  // exact-path p for the ~300 survivors: real IEEE div + libm expf
  for (int t = tid; t < C; t += NTK)
    cp[t] = expf(cv[t] / T - m) / D;
  __syncthreads();

  // exact ranking: (p desc, idx asc) — JAX top_k / stable argsort tie rule
  for (int t = tid; t < C; t += NTK) {
    float pi = cp[t];
    int   ii = ci[t];
    int r = 0;
    for (int j = 0; j < C; j++) {
      float pj = cp[j];
      r += (pj > pi) || (pj == pi && ci[j] < ii);
    }
    if (r < k) { sv[r] = pi; si[r] = ii; }
  }
  __syncthreads();

  const int kk = (k < C) ? k : C;

  // (a) speculative noise scores for ALL j < kk (parallel, overlaps cumsum)
  {
    uint32_t kn0, kn1;
    threefry2x32(0u, 0u, 0u, 1u, kn0, kn1);   // fold_in(key(0), 1)
    unsigned long long total = (unsigned long long)B * (unsigned long long)V;
    for (int j = tid; j < kk; j += NTK) {
      unsigned long long flat = (unsigned long long)b * (unsigned long long)V
                              + (unsigned long long)si[j];
      sc[j] = sv[j] / jax_noise(kn0, kn1, flat, total);
    }
  }

  // (b) top-p: serial fp32 cumsum (EXACT left-to-right association, validated),
  // LDS reads chunk-prefetched 8-at-a-time to amortize latency.
  if (tid == 0) {
    float cum = 0.f;
    int L = 1;
    bool stop = false;
    for (int j0 = 0; j0 < kk && !stop; j0 += 8) {
      // over-read past sv[kk) stays inside this block's LDS (spills into si)
      float t0 = sv[j0],     t1 = sv[j0 + 1], t2 = sv[j0 + 2], t3 = sv[j0 + 3];
      float t4 = sv[j0 + 4], t5 = sv[j0 + 5], t6 = sv[j0 + 6], t7 = sv[j0 + 7];
      float tt[8] = {t0, t1, t2, t3, t4, t5, t6, t7};
#pragma unroll
      for (int q = 0; q < 8; q++) {
        int j = j0 + q;
        if (j >= kk) { stop = true; break; }
        cum += tt[q];
        if (j == 0) continue;
        if (cum <= 0.9f) L = j + 1;
        else { stop = true; break; }
      }
    }
    L_sh = L;
  }
  __syncthreads();

  // exact wave-parallel argmax over j < L: total order (score desc, idx asc)
  if (wave == 0) {
    const int L = L_sh;
    float bs = -1.0f;
    int   bi = INT_MAX;
    for (int j = lane; j < L; j += 64) {
      float s = sc[j];
      int   ix = si[j];
      if (s > bs || (s == bs && ix < bi)) { bs = s; bi = ix; }
    }
    for (int off = 32; off; off >>= 1) {
      float os = __shfl_down(bs, off);
      int   oi = __shfl_down(bi, off);
      if (os > bs || (os == bs && oi < bi)) { bs = os; bi = oi; }
    }
    if (lane == 0) out[b] = bi;
  }
}

extern "C" void kernel_launch(void* const* d_in, const int* in_sizes, int n_in,
                              void* d_out, int out_size, void* d_ws, size_t ws_size,
                              hipStream_t stream) {
  const float* logits = (const float*)d_in[0];
  const float* temps  = (const float*)d_in[1];
  const int*   topk   = (const int*)d_in[2];
  int* out = (int*)d_out;

  int B = in_sizes[1];
  int V = in_sizes[0] / B;

  // One block per row; no workspace, single launch.
  sampler_fused<<<dim3(B), dim3(NTK), 0, stream>>>(logits, temps, topk, out, B, V);
}